// Round 4
// baseline (689.219 us; speedup 1.0000x reference)
//
#include <hip/hip_runtime.h>

// ---------------------------------------------------------------------------
// LlamaAttention fwd: B=1, S=2048, HID=4096, NH=32, NKV=8, HD=128, GQA x4.
// fp32 in/out; bf16 MFMA internally. R4: column-panel-major GEMM dispatch
// (L3 reuse), 128-q-row flash attention (64 MFMA per barrier pair).
// ---------------------------------------------------------------------------

typedef __bf16 bf16_t;
typedef bf16_t bf16x8_t __attribute__((ext_vector_type(8)));
typedef float f32x4_t __attribute__((ext_vector_type(4)));

#define S_LEN 2048
#define HID 4096
#define NH 32
#define NKV 8
#define HD 128
#define KV_DIM 1024
#define QKV_DIM 6144                 // 4096 q | 1024 k | 1024 v
#define SCALE 0.08838834764831845f   // 1/sqrt(128)

// -------- persistent device scratch ----------------------------------------
__device__ __align__(16) bf16_t g_hsb[(size_t)S_LEN * HID];
__device__ __align__(16) bf16_t g_wqkvT[(size_t)QKV_DIM * HID];  // [n][k]
__device__ __align__(16) bf16_t g_woT[(size_t)HID * HID];        // [n][k]
__device__ __align__(16) bf16_t g_qkv[(size_t)S_LEN * QKV_DIM];  // post-RoPE
__device__ __align__(16) bf16_t g_vT[(size_t)NKV * HD * S_LEN];  // [kvh][d][s]
__device__ __align__(16) bf16_t g_ao[(size_t)S_LEN * HID];       // attn out

// async global->LDS, 16B per lane; LDS dest is wave-uniform base + lane*16
__device__ __forceinline__ void gl_lds16(const bf16_t* g, bf16_t* l) {
  __builtin_amdgcn_global_load_lds(
      (const __attribute__((address_space(1))) void*)g,
      (__attribute__((address_space(3))) void*)l, 16, 0, 0);
}

// ---------------------------------------------------------------------------
__global__ __launch_bounds__(256) void cast_f32_bf16(
    const float* __restrict__ in, bf16_t* __restrict__ out)
{
  size_t i = ((size_t)blockIdx.x * 256 + threadIdx.x) * 8;
  float4 a = *(const float4*)(in + i);
  float4 b = *(const float4*)(in + i + 4);
  bf16x8_t r;
  r[0] = (bf16_t)a.x; r[1] = (bf16_t)a.y; r[2] = (bf16_t)a.z; r[3] = (bf16_t)a.w;
  r[4] = (bf16_t)b.x; r[5] = (bf16_t)b.y; r[6] = (bf16_t)b.z; r[7] = (bf16_t)b.w;
  *(bf16x8_t*)(out + i) = r;
}

// ---------------------------------------------------------------------------
// Transpose+cast: in fp32 [R][C] stride is -> out bf16 [C][R] stride os.
// ---------------------------------------------------------------------------
__global__ __launch_bounds__(256) void transpose_f32_bf16(
    const float* __restrict__ in, bf16_t* __restrict__ out, int is, int os)
{
  __shared__ __align__(16) bf16_t T[64 * 72];
  int r0 = blockIdx.x * 64, c0 = blockIdx.y * 64;
  int t = threadIdx.x;
#pragma unroll
  for (int it = 0; it < 2; ++it) {
    int idx = t + it * 256;
    int r = idx >> 3, c8 = (idx & 7) * 8;
    const float* p = in + (size_t)(r0 + r) * is + c0 + c8;
    float4 a = *(const float4*)p;
    float4 b = *(const float4*)(p + 4);
    bf16x8_t x;
    x[0] = (bf16_t)a.x; x[1] = (bf16_t)a.y; x[2] = (bf16_t)a.z; x[3] = (bf16_t)a.w;
    x[4] = (bf16_t)b.x; x[5] = (bf16_t)b.y; x[6] = (bf16_t)b.z; x[7] = (bf16_t)b.w;
    *(bf16x8_t*)(T + r * 72 + c8) = x;
  }
  __syncthreads();
#pragma unroll
  for (int it = 0; it < 2; ++it) {
    int idx = t + it * 256;
    int c = idx >> 3, r8 = (idx & 7) * 8;
    bf16x8_t x;
#pragma unroll
    for (int i = 0; i < 8; ++i) x[i] = T[(r8 + i) * 72 + c];
    *(bf16x8_t*)(out + (size_t)(c0 + c) * os + r0 + r8) = x;
  }
}

// ---------------------------------------------------------------------------
// bf16 batched transpose (V -> V^T per kv head).
// ---------------------------------------------------------------------------
__global__ __launch_bounds__(256) void transpose_bf16(
    const bf16_t* __restrict__ in, bf16_t* __restrict__ out,
    int is, int os, int in_b, int out_b)
{
  __shared__ __align__(16) bf16_t T[64 * 72];
  const bf16_t* inp = in + (size_t)blockIdx.z * in_b;
  bf16_t* outp = out + (size_t)blockIdx.z * out_b;
  int r0 = blockIdx.x * 64, c0 = blockIdx.y * 64;
  int t = threadIdx.x;
#pragma unroll
  for (int it = 0; it < 2; ++it) {
    int idx = t + it * 256;
    int r = idx >> 3, c8 = (idx & 7) * 8;
    *(bf16x8_t*)(T + r * 72 + c8) =
        *(const bf16x8_t*)(inp + (size_t)(r0 + r) * is + c0 + c8);
  }
  __syncthreads();
#pragma unroll
  for (int it = 0; it < 2; ++it) {
    int idx = t + it * 256;
    int c = idx >> 3, r8 = (idx & 7) * 8;
    bf16x8_t x;
#pragma unroll
    for (int i = 0; i < 8; ++i) x[i] = T[(r8 + i) * 72 + c];
    *(bf16x8_t*)(outp + (size_t)(c0 + c) * os + r0 + r8) = x;
  }
}

// ---------------------------------------------------------------------------
// m97-style GEMM: C[M,N] = A[M,K] @ Bt[N,K]^T. 128x128 tile, BK=32, 4 waves,
// 1-D grid, column-panel-major mapping (bm = id % MB): the MB m-blocks of one
// B-panel dispatch consecutively -> B panel + all of A stay L3-resident.
// ---------------------------------------------------------------------------
template <typename CT>
__global__ __launch_bounds__(256) void gemm128(
    const bf16_t* __restrict__ A, const bf16_t* __restrict__ Bt,
    CT* __restrict__ C, int K, int N, int MB)
{
  __shared__ __align__(16) bf16_t As[128 * 32];   // [m][k]
  __shared__ __align__(16) bf16_t Bs[128 * 32];   // [n][k]
  int t = threadIdx.x;
  int wave = t >> 6, lane = t & 63, ln = lane & 15, lq = lane >> 4;
  int id = blockIdx.x;
  int m0 = (id % MB) * 128, n0 = (id / MB) * 128;
  int wm = (wave >> 1) * 64, wn = (wave & 1) * 64;
  int srow = wave * 16 + (lane >> 2);
  int skc = (lane & 3) * 8;
  const bf16_t* Ag0 = A + (size_t)(m0 + srow) * K + skc;
  const bf16_t* Ag1 = A + (size_t)(m0 + 64 + srow) * K + skc;
  const bf16_t* Bg0 = Bt + (size_t)(n0 + srow) * K + skc;
  const bf16_t* Bg1 = Bt + (size_t)(n0 + 64 + srow) * K + skc;
  bf16_t* Al0 = As + (wave * 16) * 32;
  bf16_t* Al1 = As + (64 + wave * 16) * 32;
  bf16_t* Bl0 = Bs + (wave * 16) * 32;
  bf16_t* Bl1 = Bs + (64 + wave * 16) * 32;
  f32x4_t acc[4][4] = {};
  for (int k0 = 0; k0 < K; k0 += 32) {
    __syncthreads();
    gl_lds16(Ag0 + k0, Al0);
    gl_lds16(Ag1 + k0, Al1);
    gl_lds16(Bg0 + k0, Bl0);
    gl_lds16(Bg1 + k0, Bl1);
    __syncthreads();
    bf16x8_t af[4], bfr[4];
#pragma unroll
    for (int i = 0; i < 4; ++i) {
      af[i]  = *(const bf16x8_t*)(As + (wm + i * 16 + ln) * 32 + lq * 8);
      bfr[i] = *(const bf16x8_t*)(Bs + (wn + i * 16 + ln) * 32 + lq * 8);
    }
#pragma unroll
    for (int mt = 0; mt < 4; ++mt)
#pragma unroll
      for (int nt = 0; nt < 4; ++nt)
        acc[mt][nt] = __builtin_amdgcn_mfma_f32_16x16x32_bf16(
            af[mt], bfr[nt], acc[mt][nt], 0, 0, 0);
  }
#pragma unroll
  for (int mt = 0; mt < 4; ++mt)
#pragma unroll
    for (int nt = 0; nt < 4; ++nt)
#pragma unroll
      for (int r = 0; r < 4; ++r)
        C[(size_t)(m0 + wm + mt * 16 + lq * 4 + r) * N + n0 + wn + nt * 16 + ln] =
            (CT)acc[mt][nt][r];
}

// ---------------------------------------------------------------------------
// RoPE in-place on fused qkv layout [s][6144]; cos/sin fp32 [S][128].
// ---------------------------------------------------------------------------
__global__ __launch_bounds__(256) void rope_kernel(
    bf16_t* __restrict__ qkv, const float* __restrict__ cs,
    const float* __restrict__ sn)
{
  int idx = blockIdx.x * 256 + threadIdx.x;
  int d = idx & 63;
  int h = (idx >> 6) % (NH + NKV);
  int s = idx / (64 * (NH + NKV));
  float c = cs[s * HD + d], si = sn[s * HD + d];
  bf16_t* base = qkv + (size_t)s * QKV_DIM +
                 ((h < NH) ? h * HD : HID + (h - NH) * HD);
  float x1 = (float)base[d], x2 = (float)base[d + 64];
  base[d]      = (bf16_t)(x1 * c - x2 * si);
  base[d + 64] = (bf16_t)(x2 * c + x1 * si);
}

// ---------------------------------------------------------------------------
// Flash attention, causal, GQA. 128 q-rows/block (32 per wave = 2 row-tiles),
// BK=64 -> 64 MFMA per barrier pair. Longest-first: qblk = 15 - bid/32.
// LDS 54 KB -> 2 blocks/CU; grid 512 = 2/CU.
// ---------------------------------------------------------------------------
__global__ __launch_bounds__(256) void attn_kernel(
    const bf16_t* __restrict__ QKV, const bf16_t* __restrict__ VT,
    bf16_t* __restrict__ O)
{
  __shared__ __align__(16) bf16_t Ks[64 * 136];    // [kpos][d], pad 128->136
  __shared__ __align__(16) bf16_t Vs[128 * 72];    // [d][kpos], pad 64->72
  __shared__ __align__(16) bf16_t Ps[4 * 32 * 72]; // per-wave [32 q][64 k]
  int t = threadIdx.x, wave = t >> 6, lane = t & 63;
  int ln = lane & 15, lq = lane >> 4;
  int bid = blockIdx.x;
  int qblk = (S_LEN / 128 - 1) - (bid >> 5);       // 15..0, longest first
  int head = bid & 31, kvh = head >> 2;
  int q0 = qblk * 128;

  bf16x8_t qf[2][4];
#pragma unroll
  for (int rt = 0; rt < 2; ++rt)
#pragma unroll
    for (int kk = 0; kk < 4; ++kk)
      qf[rt][kk] = *(const bf16x8_t*)(
          QKV + (size_t)(q0 + wave * 32 + rt * 16 + ln) * QKV_DIM +
          head * HD + kk * 32 + lq * 8);

  f32x4_t oa[2][8] = {};
  float m_r[2][4], l_r[2][4];
#pragma unroll
  for (int rt = 0; rt < 2; ++rt)
#pragma unroll
    for (int r = 0; r < 4; ++r) { m_r[rt][r] = -1e30f; l_r[rt][r] = 0.f; }

  int krow = t >> 4, kdc = (t & 15) * 8;   // Ks staging: 16 rows/pass
  int vrow = t >> 3, vkc = (t & 7) * 8;    // Vs staging: 32 rows/pass
  const bf16_t* Kg = QKV + HID + (size_t)kvh * HD;
  const bf16_t* Vg = VT + (size_t)kvh * HD * S_LEN;

  int ktend = 2 * qblk + 1;
  for (int kt = 0; kt <= ktend; ++kt) {
    int kb = kt * 64;
    __syncthreads();
#pragma unroll
    for (int p = 0; p < 4; ++p) {
      int r_ = p * 16 + krow;
      *(bf16x8_t*)(Ks + r_ * 136 + kdc) =
          *(const bf16x8_t*)(Kg + (size_t)(kb + r_) * QKV_DIM + kdc);
      int d_ = p * 32 + vrow;
      *(bf16x8_t*)(Vs + d_ * 72 + vkc) =
          *(const bf16x8_t*)(Vg + (size_t)d_ * S_LEN + kb + vkc);
    }
    __syncthreads();

    // S = Q @ K^T : 2 row-tiles x 4 col-tiles, K-frag loaded once per (nt,kk)
    f32x4_t sv[2][4] = {};
#pragma unroll
    for (int nt = 0; nt < 4; ++nt)
#pragma unroll
      for (int kk = 0; kk < 4; ++kk) {
        bf16x8_t kf = *(const bf16x8_t*)(Ks + (nt * 16 + ln) * 136 +
                                         kk * 32 + lq * 8);
        sv[0][nt] = __builtin_amdgcn_mfma_f32_16x16x32_bf16(qf[0][kk], kf,
                                                            sv[0][nt], 0, 0, 0);
        sv[1][nt] = __builtin_amdgcn_mfma_f32_16x16x32_bf16(qf[1][kk], kf,
                                                            sv[1][nt], 0, 0, 0);
      }

    float p_[2][4][4];                     // [rt][nt][r]
    if (kt >= 2 * qblk) {                  // diagonal region: mask
#pragma unroll
      for (int rt = 0; rt < 2; ++rt)
#pragma unroll
        for (int nt = 0; nt < 4; ++nt)
#pragma unroll
          for (int r = 0; r < 4; ++r) {
            int rowg = q0 + wave * 32 + rt * 16 + lq * 4 + r;
            int colg = kb + nt * 16 + ln;
            p_[rt][nt][r] = (colg <= rowg) ? sv[rt][nt][r] * SCALE : -1e30f;
          }
    } else {
#pragma unroll
      for (int rt = 0; rt < 2; ++rt)
#pragma unroll
        for (int nt = 0; nt < 4; ++nt)
#pragma unroll
          for (int r = 0; r < 4; ++r) p_[rt][nt][r] = sv[rt][nt][r] * SCALE;
    }

#pragma unroll
    for (int rt = 0; rt < 2; ++rt) {
      float mx[4], al[4], rs[4];
#pragma unroll
      for (int r = 0; r < 4; ++r)
        mx[r] = fmaxf(fmaxf(p_[rt][0][r], p_[rt][1][r]),
                      fmaxf(p_[rt][2][r], p_[rt][3][r]));
#pragma unroll
      for (int off = 8; off >= 1; off >>= 1)
#pragma unroll
        for (int r = 0; r < 4; ++r)
          mx[r] = fmaxf(mx[r], __shfl_xor(mx[r], off, 64));
#pragma unroll
      for (int r = 0; r < 4; ++r) {
        float mn = fmaxf(m_r[rt][r], mx[r]);
        al[r] = __expf(m_r[rt][r] - mn);
        m_r[rt][r] = mn;
        rs[r] = 0.f;
#pragma unroll
        for (int nt = 0; nt < 4; ++nt) {
          p_[rt][nt][r] = __expf(p_[rt][nt][r] - mn);
          rs[r] += p_[rt][nt][r];
        }
      }
#pragma unroll
      for (int off = 8; off >= 1; off >>= 1)
#pragma unroll
        for (int r = 0; r < 4; ++r) rs[r] += __shfl_xor(rs[r], off, 64);
#pragma unroll
      for (int r = 0; r < 4; ++r) l_r[rt][r] = l_r[rt][r] * al[r] + rs[r];
#pragma unroll
      for (int dt = 0; dt < 8; ++dt)
#pragma unroll
        for (int r = 0; r < 4; ++r) oa[rt][dt][r] *= al[r];
    }

    // P: C/D layout -> per-wave LDS slice -> A-operand layout (no barrier)
    bf16_t* myP = Ps + wave * 32 * 72;
#pragma unroll
    for (int rt = 0; rt < 2; ++rt)
#pragma unroll
      for (int nt = 0; nt < 4; ++nt)
#pragma unroll
        for (int r = 0; r < 4; ++r)
          myP[(rt * 16 + lq * 4 + r) * 72 + nt * 16 + ln] = (bf16_t)p_[rt][nt][r];
    bf16x8_t pf[2][2];
#pragma unroll
    for (int rt = 0; rt < 2; ++rt) {
      pf[rt][0] = *(const bf16x8_t*)(myP + (rt * 16 + ln) * 72 + lq * 8);
      pf[rt][1] = *(const bf16x8_t*)(myP + (rt * 16 + ln) * 72 + 32 + lq * 8);
    }
#pragma unroll
    for (int dt = 0; dt < 8; ++dt) {
      bf16x8_t v0 = *(const bf16x8_t*)(Vs + (dt * 16 + ln) * 72 + lq * 8);
      bf16x8_t v1 = *(const bf16x8_t*)(Vs + (dt * 16 + ln) * 72 + 32 + lq * 8);
#pragma unroll
      for (int rt = 0; rt < 2; ++rt) {
        oa[rt][dt] = __builtin_amdgcn_mfma_f32_16x16x32_bf16(pf[rt][0], v0,
                                                             oa[rt][dt], 0, 0, 0);
        oa[rt][dt] = __builtin_amdgcn_mfma_f32_16x16x32_bf16(pf[rt][1], v1,
                                                             oa[rt][dt], 0, 0, 0);
      }
    }
  }

#pragma unroll
  for (int rt = 0; rt < 2; ++rt)
#pragma unroll
    for (int dt = 0; dt < 8; ++dt)
#pragma unroll
      for (int r = 0; r < 4; ++r) {
        int row = q0 + wave * 32 + rt * 16 + lq * 4 + r;
        O[(size_t)row * HID + head * HD + dt * 16 + ln] =
            (bf16_t)(oa[rt][dt][r] / l_r[rt][r]);
      }
}

// ---------------------------------------------------------------------------
extern "C" void kernel_launch(void* const* d_in, const int* in_sizes, int n_in,
                              void* d_out, int out_size, void* d_ws, size_t ws_size,
                              hipStream_t stream)
{
  (void)in_sizes; (void)n_in; (void)out_size; (void)d_ws; (void)ws_size;
  const float* hs = (const float*)d_in[0];
  // d_in[1] = attention_mask (pure causal) -> analytic
  const float* wq = (const float*)d_in[2];
  const float* wk = (const float*)d_in[3];
  const float* wv = (const float*)d_in[4];
  const float* wo = (const float*)d_in[5];
  const float* cs = (const float*)d_in[6];
  const float* sn = (const float*)d_in[7];
  float* out = (float*)d_out;

  bf16_t *hsb, *wqkvT, *woT, *qkv, *vT, *ao;
  hipGetSymbolAddress((void**)&hsb,   HIP_SYMBOL(g_hsb));
  hipGetSymbolAddress((void**)&wqkvT, HIP_SYMBOL(g_wqkvT));
  hipGetSymbolAddress((void**)&woT,   HIP_SYMBOL(g_woT));
  hipGetSymbolAddress((void**)&qkv,   HIP_SYMBOL(g_qkv));
  hipGetSymbolAddress((void**)&vT,    HIP_SYMBOL(g_vT));
  hipGetSymbolAddress((void**)&ao,    HIP_SYMBOL(g_ao));

  // hidden_states fp32 -> bf16
  cast_f32_bf16<<<(S_LEN * HID) / (256 * 8), 256, 0, stream>>>(hs, hsb);

  // weight transposes (+cast) into fused wqkvT rows [0,4096,5120] and woT
  transpose_f32_bf16<<<dim3(64, 64), 256, 0, stream>>>(wq, wqkvT, HID, HID);
  transpose_f32_bf16<<<dim3(64, 16), 256, 0, stream>>>(
      wk, wqkvT + (size_t)HID * HID, KV_DIM, HID);
  transpose_f32_bf16<<<dim3(64, 16), 256, 0, stream>>>(
      wv, wqkvT + (size_t)(HID + KV_DIM) * HID, KV_DIM, HID);
  transpose_f32_bf16<<<dim3(64, 64), 256, 0, stream>>>(wo, woT, HID, HID);

  // fused QKV projection: [2048,4096] @ [6144,4096]^T -> [2048,6144]
  gemm128<bf16_t><<<dim3((S_LEN / 128) * (QKV_DIM / 128)), 256, 0, stream>>>(
      hsb, wqkvT, qkv, HID, QKV_DIM, S_LEN / 128);

  // RoPE on q and k (in fused layout)
  rope_kernel<<<(S_LEN * (NH + NKV) * 64) / 256, 256, 0, stream>>>(qkv, cs, sn);

  // v section [s][kvh*128+d] -> vT[kvh][d][s]
  transpose_bf16<<<dim3(S_LEN / 64, HD / 64, NKV), 256, 0, stream>>>(
      qkv + HID + KV_DIM, vT, QKV_DIM, S_LEN, HD, HD * S_LEN);

  // attention (128 q-rows/block, longest first)
  attn_kernel<<<dim3((S_LEN / 128) * NH), 256, 0, stream>>>(qkv, vT, ao);

  // output projection (fp32 out)
  gemm128<float><<<dim3((S_LEN / 128) * (HID / 128)), 256, 0, stream>>>(
      ao, woT, out, HID, HID, S_LEN / 128);
}